// Round 15
// baseline (138.845 us; speedup 1.0000x reference)
//
#include <hip/hip_runtime.h>

// ---------------------------------------------------------------------------
// GeneratorInitial via split-f16 MFMA (hi/lo, f32-class accuracy) with the
// depthwise 3x3 folded into conv2 as a per-batch composite 11x11 conv:
//   out = W2 (*) (F_b (*) y1) = Wc_b (*) y1,  Wc_b = F_b (*) W2  (both linear)
//
//   k_prep:    filter MLP -> F_b; Wc_b = F_b (*) W2; emit pre-split per-lane
//              MFMA B-fragments for W1 (9 dy) and Wc_b (11 dy).
//   k_conv1:   in f32 -> 9x9 conv (MFMA) -> relu -> y1 (hi,lo f16 interleaved)
//   k_dwconv2: y1 -> 11x11 per-batch conv (MFMA) -> relu -> pixnorm -> out
//
// MFMA scheme per output row: dy-rowconvs, each M16 x N16 x K64:
//   M = 16 pixel groups (x stride 4), N = (shift s 0..3) x (out ch f 0..3),
//   K = 16 e-positions x 4 in-ch, k = st*32 + 8g + j.  B[k][n] = W[dy][e-s][c][f].
//
// R15: per-kernel tile tuning.  R13/R14 evidence: conv1 staging is VALU-heavy
// (split_f x4/pixel) -> wants LARGE tiles (32-row, R13 config, ~49us);
// dwconv2 staging is a cheap de-interleave -> wants OCCUPANCY (8-row tiles,
// LDS 21.9KB -> 7 blocks/CU = 28 waves; halo re-reads absorbed by L3 since
// y1 (65MB) is L3-resident -- R14 FETCH 46MB < 65MB).  Chunked ir-major
// inner structure unchanged (no spill, no mass re-read since R13).
// ---------------------------------------------------------------------------

typedef _Float16 f16;
typedef _Float16 f16x2 __attribute__((ext_vector_type(2)));
typedef _Float16 f16x4 __attribute__((ext_vector_type(4)));
typedef _Float16 f16x8 __attribute__((ext_vector_type(8)));
typedef float f32x4 __attribute__((ext_vector_type(4)));

static __device__ __forceinline__ f32x4 mfma16(f16x8 a, f16x8 b, f32x4 c) {
    return __builtin_amdgcn_mfma_f32_16x16x32_f16(a, b, c, 0, 0, 0);
}

static __device__ __forceinline__ float silu_f(float x) {
    return x / (1.0f + expf(-x));
}

// returns (hi, lo) with x ~= hi + lo
static __device__ __forceinline__ f16x2 split_f(float x) {
    f16x2 r;
    r[0] = (f16)x;
    r[1] = (f16)(x - (float)r[0]);
    return r;
}

// One dy-chunk [D0, D0+ND): load B (plain), stream A ir-major, 3-term MFMA.
// NR output rows per wave (acc[NR]).  All indices compile-time after unroll.
template <int D0, int ND, int NR>
static __device__ __forceinline__ void conv_chunk(
    const f16x8* __restrict__ bbase, const f16x4 (*__restrict__ s_hi)[76],
    const f16x4 (*__restrict__ s_lo)[76], const int wrow, const int aoff,
    f32x4* __restrict__ acc)
{
    f16x8 Bh[ND], Bl[ND];
#pragma unroll
    for (int j = 0; j < ND; ++j) {
        Bh[j] = bbase[(D0 + j) * 256];
        Bl[j] = bbase[(D0 + j) * 256 + 64];
    }
    __builtin_amdgcn_s_setprio(1);
#pragma unroll
    for (int ir = D0; ir < D0 + ND + NR - 1; ++ir) {
        const f16x8 Ah = *(const f16x8*)(&s_hi[wrow + ir][0] + aoff);
        const f16x8 Al = *(const f16x8*)(&s_lo[wrow + ir][0] + aoff);
#pragma unroll
        for (int r = 0; r < NR; ++r) {
            const int dy = ir - r;
            if (dy >= D0 && dy < D0 + ND) {
                acc[r] = mfma16(Ah, Bh[dy - D0], acc[r]);
                acc[r] = mfma16(Ah, Bl[dy - D0], acc[r]);
                acc[r] = mfma16(Al, Bh[dy - D0], acc[r]);
            }
        }
    }
    __builtin_amdgcn_s_setprio(0);
}

// --- prep: per-batch filters, composite weights, pre-split B-fragments
//     fragW1: [9][st 2][hl 2][lane 64] f16x8      (batch-independent)
//     fragW2: [16][11][st 2][hl 2][lane 64] f16x8 (per-batch composite)
__global__ __launch_bounds__(256) void k_prep(
    const float* __restrict__ params, const float* __restrict__ W_emb,
    const float* __restrict__ b_emb, const float* __restrict__ KT,
    const float* __restrict__ bT, const float* __restrict__ W1,
    const float* __restrict__ W2,
    f16x8* __restrict__ fragW1, f16x8* __restrict__ fragW2)
{
    __shared__ float s_emb[128];
    __shared__ float s_filt[36];      // [i2*3+j2][c]
    __shared__ float s_wc[1936];      // [dy][dx][c][f], 11x11x4x4
    const int t = threadIdx.x, b = blockIdx.x;

    if (t < 128) {
        float sv = b_emb[t];
#pragma unroll
        for (int p = 0; p < 8; ++p)
            sv = fmaf(params[b * 8 + p], W_emb[p * 128 + t], sv);
        s_emb[t] = silu_f(sv);
    }
    __syncthreads();
    if (t < 36) {
        const int ij = t >> 2, ff = t & 3;
        float sv = bT[ff];
        for (int c = 0; c < 128; ++c)
            sv = fmaf(s_emb[c], KT[(ij * 128 + c) * 4 + ff], sv);
        s_filt[t] = silu_f(sv);
    }
    __syncthreads();

    // composite Wc[dy][dx][c][f] = sum_{i2,j2} F[i2][j2][c] * W2[dy-i2][dx-j2][c][f]
    for (int i = t; i < 1936; i += 256) {
        const int f = i & 3, c = (i >> 2) & 3;
        const int dxy = i >> 4, dx = dxy % 11, dy = dxy / 11;
        float sv = 0.f;
#pragma unroll
        for (int i2 = 0; i2 < 3; ++i2)
#pragma unroll
            for (int j2 = 0; j2 < 3; ++j2) {
                const int a = dy - i2, bb = dx - j2;
                if (a >= 0 && a < 9 && bb >= 0 && bb < 9)
                    sv = fmaf(s_filt[(i2 * 3 + j2) * 4 + c],
                              W2[((a * 9 + bb) * 4 + c) * 4 + f], sv);
            }
        s_wc[i] = sv;
    }
    __syncthreads();

    // B-fragments for the composite (per batch)
    for (int fi = t; fi < 11 * 256; fi += 256) {
        const int dy = fi >> 8, rem = fi & 255;
        const int st = (rem >> 7) & 1, hl = (rem >> 6) & 1, lane = rem & 63;
        const int g = lane >> 4, n = lane & 15, s = n >> 2, f = n & 3;
        f16x8 v;
#pragma unroll
        for (int j = 0; j < 8; ++j) {
            const int k = st * 32 + g * 8 + j;
            const int e = k >> 2, c = k & 3, dx = e - s;
            const float wv = (dx >= 0 && dx < 11)
                ? s_wc[((dy * 11 + dx) * 4 + c) * 4 + f] : 0.f;
            const f16x2 hlv = split_f(wv);
            v[j] = hl ? hlv[1] : hlv[0];
        }
        fragW2[((size_t)b * 11 + dy) * 256 + rem] = v;
    }

    // B-fragments for W1 (batch-independent; block 0 only)
    if (b == 0) {
        for (int fi = t; fi < 9 * 256; fi += 256) {
            const int dy = fi >> 8, rem = fi & 255;
            const int st = (rem >> 7) & 1, hl = (rem >> 6) & 1, lane = rem & 63;
            const int g = lane >> 4, n = lane & 15, s = n >> 2, f = n & 3;
            f16x8 v;
#pragma unroll
            for (int j = 0; j < 8; ++j) {
                const int k = st * 32 + g * 8 + j;
                const int e = k >> 2, c = k & 3, dx = e - s;
                const float wv = (dx >= 0 && dx < 9)
                    ? W1[((dy * 9 + dx) * 4 + c) * 4 + f] : 0.f;
                const f16x2 hlv = split_f(wv);
                v[j] = hl ? hlv[1] : hlv[0];
            }
            fragW1[(size_t)dy * 256 + rem] = v;
        }
    }
}

// --- conv1: [16,512,512,4] f32 -> relu -> y1 [16,504,504] x (h,l)x4 f16
//     32-row tiles (R13 config -- staging is VALU-heavy, amortize the halo)
__global__ __launch_bounds__(256, 2) void k_conv1(
    const float* __restrict__ in, const float* __restrict__ b1,
    const f16x8* __restrict__ fragW1, f16* __restrict__ y1)
{
    __shared__ f16x4 s_hi[40][76];
    __shared__ f16x4 s_lo[40][76];
    const int t = threadIdx.x;
    const int x0 = blockIdx.x * 64, y0 = blockIdx.y * 32, b = blockIdx.z;

    const float4* inp = (const float4*)in + (size_t)b * (512 * 512);
    for (int i = t; i < 40 * 76; i += 256) {
        const int rr = i / 76, cc = i % 76;
        const int gy = y0 + rr, gx = x0 + cc;
        float4 v = make_float4(0.f, 0.f, 0.f, 0.f);
        if (gy < 512 && gx < 512) v = inp[gy * 512 + gx];
        f16x4 h, l;
        const f16x2 p0 = split_f(v.x), p1 = split_f(v.y);
        const f16x2 p2 = split_f(v.z), p3 = split_f(v.w);
        h[0] = p0[0]; l[0] = p0[1]; h[1] = p1[0]; l[1] = p1[1];
        h[2] = p2[0]; l[2] = p2[1]; h[3] = p3[0]; l[3] = p3[1];
        s_hi[rr][cc] = h; s_lo[rr][cc] = l;
    }

    const int lane = t & 63, w = t >> 6;
    const int g = lane >> 4, n = lane & 15, s = n >> 2, f = n & 3;

    __syncthreads();

    const float bias = b1[f];
    f32x4 acc[8];
#pragma unroll
    for (int r = 0; r < 8; ++r) acc[r] = (f32x4){bias, bias, bias, bias};

    const int ai = 4 * (lane & 15) + 2 * g;
#pragma unroll
    for (int st = 0; st < 2; ++st) {
        const f16x8* bbase = fragW1 + st * 128 + lane;
        const int aoff = ai + st * 8;
        conv_chunk<0, 5, 8>(bbase, s_hi, s_lo, w * 8, aoff, acc);
        conv_chunk<5, 4, 8>(bbase, s_hi, s_lo, w * 8, aoff, acc);
    }

    // D: col n=(s,f); row m=4g+q; x = x0+16g+4q+s; store (h,l) f16x2
    const int xb = x0 + 16 * g + s;
#pragma unroll
    for (int r = 0; r < 8; ++r) {
        const int yr = y0 + w * 8 + r;
        if (yr >= 504) continue;
        const size_t rowbase = ((size_t)(b * 504 + yr) * 504) * 8 + f * 2;
#pragma unroll
        for (int q = 0; q < 4; ++q) {
            const int x = xb + 4 * q;
            if (x < 504) {
                const float v = fmaxf(acc[r][q], 0.f);
                *(f16x2*)(y1 + rowbase + (size_t)x * 8) = split_f(v);
            }
        }
    }
}

// --- composite 11x11 per-batch conv on y1 + relu + pixnorm -> out f32
//     8-row tiles: LDS 18x76x16B = 21.9KB -> 7 blocks/CU (staging is cheap)
__global__ __launch_bounds__(256, 2) void k_dwconv2(
    const f16* __restrict__ y1, const float* __restrict__ b2,
    const f16x8* __restrict__ fragW2, float* __restrict__ out)
{
    __shared__ f16x4 s_hi[18][76];
    __shared__ f16x4 s_lo[18][76];
    const int t = threadIdx.x;
    const int x0 = blockIdx.x * 64, y0 = blockIdx.y * 8, b = blockIdx.z;

    // stage y1 with halo (-1 .. +9 beyond tile), zero outside [0,504)^2
    for (int i = t; i < 18 * 76; i += 256) {
        const int rr = i / 76, cc = i % 76;
        const int gy = y0 - 1 + rr, gx = x0 - 1 + cc;
        f16x4 h, l;
        if (gy >= 0 && gy < 504 && gx >= 0 && gx < 504) {
            const f16x8 p = *(const f16x8*)(y1 + ((size_t)(b * 504 + gy) * 504 +
                                                  (size_t)gx) * 8);
            h[0] = p[0]; l[0] = p[1]; h[1] = p[2]; l[1] = p[3];
            h[2] = p[4]; l[2] = p[5]; h[3] = p[6]; l[3] = p[7];
        } else {
            h[0] = h[1] = h[2] = h[3] = (f16)0.f;
            l[0] = l[1] = l[2] = l[3] = (f16)0.f;
        }
        s_hi[rr][cc] = h; s_lo[rr][cc] = l;
    }

    const int lane = t & 63, w = t >> 6;
    const int g = lane >> 4, n = lane & 15, s = n >> 2, f = n & 3;
    const f16x8* fr = fragW2 + (size_t)b * 11 * 256;

    __syncthreads();

    const float bias = b2[f];
    f32x4 acc[2];
#pragma unroll
    for (int r = 0; r < 2; ++r) acc[r] = (f32x4){bias, bias, bias, bias};

    const int ai = 4 * (lane & 15) + 2 * g;
#pragma unroll
    for (int st = 0; st < 2; ++st) {
        const f16x8* bbase = fr + st * 128 + lane;
        const int aoff = ai + st * 8;
        conv_chunk<0, 4, 2>(bbase, s_hi, s_lo, w * 2, aoff, acc);
        conv_chunk<4, 4, 2>(bbase, s_hi, s_lo, w * 2, aoff, acc);
        conv_chunk<8, 3, 2>(bbase, s_hi, s_lo, w * 2, aoff, acc);
    }

    // epilogue: relu -> pixnorm across channels (lanes n^1, n^2) -> f32 store
    const int xb = x0 + 16 * g + s;
#pragma unroll
    for (int r = 0; r < 2; ++r) {
        const int yr = y0 + w * 2 + r;
        const size_t rowbase = ((size_t)((size_t)b * 496 + yr) * 496) * 4 + f;
#pragma unroll
        for (int q = 0; q < 4; ++q) {
            float v = fmaxf(acc[r][q], 0.f);
            float sq = v * v;
            sq += __shfl_xor(sq, 1);
            sq += __shfl_xor(sq, 2);
            const float sc = rsqrtf(sq * 0.25f + 1e-8f);
            const int x = xb + 4 * q;
            if (yr < 496 && x < 496) out[rowbase + (size_t)x * 4] = v * sc;
        }
    }
}

extern "C" void kernel_launch(void* const* d_in, const int* in_sizes, int n_in,
                              void* d_out, int out_size, void* d_ws, size_t ws_size,
                              hipStream_t stream)
{
    const float* noise  = (const float*)d_in[0];
    const float* params = (const float*)d_in[1];
    const float* W_emb  = (const float*)d_in[2];
    const float* b_emb  = (const float*)d_in[3];
    const float* KT     = (const float*)d_in[4];
    const float* bT     = (const float*)d_in[5];
    const float* W1     = (const float*)d_in[6];
    const float* b1     = (const float*)d_in[7];
    const float* W2     = (const float*)d_in[8];
    const float* b2     = (const float*)d_in[9];

    float* out = (float*)d_out;
    f16*   y1  = (f16*)d_ws;  // 16*504*504*8 f16 = 65,028,096 B
    f16x8* fragW2 = (f16x8*)((char*)d_ws + 65028096);           // 720,896 B
    f16x8* fragW1 = (f16x8*)((char*)d_ws + 65028096 + 720896);  //  36,864 B

    k_prep<<<dim3(16), dim3(256), 0, stream>>>(params, W_emb, b_emb, KT, bT,
                                               W1, W2, fragW1, fragW2);

    dim3 grid(8, 16, 16);   // ceil(504/64), ceil(504/32), B
    k_conv1<<<grid, dim3(256), 0, stream>>>(noise, b1, fragW1, y1);

    dim3 grid2(8, 62, 16);  // ceil(496/64), 496/8, B
    k_dwconv2<<<grid2, dim3(256), 0, stream>>>(y1, b2, fragW2, out);
}

// Round 16
// 130.275 us; speedup vs baseline: 1.0658x; 1.0658x over previous
//
#include <hip/hip_runtime.h>

// ---------------------------------------------------------------------------
// GeneratorInitial via split-f16 MFMA (hi/lo, f32-class accuracy) with the
// depthwise 3x3 folded into conv2 as a per-batch composite 11x11 conv:
//   out = W2 (*) (F_b (*) y1) = Wc_b (*) y1,  Wc_b = F_b (*) W2  (both linear)
//
//   k_prep:    filter MLP -> F_b; Wc_b = F_b (*) W2; emit pre-split per-lane
//              MFMA B-fragments for W1 (9 dy) and Wc_b (11 dy).
//   k_conv1:   in f32 -> 9x9 conv (MFMA) -> relu -> y1 (hi,lo f16 interleaved)
//   k_dwconv2: y1 -> 11x11 per-batch conv (MFMA) -> relu -> pixnorm -> out
//
// MFMA scheme per output row: dy-rowconvs, each M16 x N16 x K64:
//   M = 16 pixel groups (x stride 4), N = (shift s 0..3) x (out ch f 0..3),
//   K = 16 e-positions x 4 in-ch, k = st*32 + 8g + j.  B[k][n] = W[dy][e-s][c][f].
//
// R16: recombine measured per-kernel optima.
//   conv1   = R13 exact: 32-row tiles, NO setprio (R13/R14/R15 subtraction:
//             setprio costs conv1 ~13us -- its VALU-heavy staging waves get
//             starved while sibling waves hold prio 1).
//   dwconv2 = R14 exact: 16-row tiles (5 blocks/CU), setprio kept (71.5us
//             measured).  R15's 8-row tiles quadrupled B-loads/row -> slower
//             despite 47% occupancy.
// ---------------------------------------------------------------------------

typedef _Float16 f16;
typedef _Float16 f16x2 __attribute__((ext_vector_type(2)));
typedef _Float16 f16x4 __attribute__((ext_vector_type(4)));
typedef _Float16 f16x8 __attribute__((ext_vector_type(8)));
typedef float f32x4 __attribute__((ext_vector_type(4)));

static __device__ __forceinline__ f32x4 mfma16(f16x8 a, f16x8 b, f32x4 c) {
    return __builtin_amdgcn_mfma_f32_16x16x32_f16(a, b, c, 0, 0, 0);
}

static __device__ __forceinline__ float silu_f(float x) {
    return x / (1.0f + expf(-x));
}

// returns (hi, lo) with x ~= hi + lo
static __device__ __forceinline__ f16x2 split_f(float x) {
    f16x2 r;
    r[0] = (f16)x;
    r[1] = (f16)(x - (float)r[0]);
    return r;
}

// One dy-chunk [D0, D0+ND): load B (plain), stream A ir-major, 3-term MFMA.
// NR output rows per wave (acc[NR]).  All indices compile-time after unroll.
template <int D0, int ND, int NR, bool PRIO>
static __device__ __forceinline__ void conv_chunk(
    const f16x8* __restrict__ bbase, const f16x4 (*__restrict__ s_hi)[76],
    const f16x4 (*__restrict__ s_lo)[76], const int wrow, const int aoff,
    f32x4* __restrict__ acc)
{
    f16x8 Bh[ND], Bl[ND];
#pragma unroll
    for (int j = 0; j < ND; ++j) {
        Bh[j] = bbase[(D0 + j) * 256];
        Bl[j] = bbase[(D0 + j) * 256 + 64];
    }
    if (PRIO) __builtin_amdgcn_s_setprio(1);
#pragma unroll
    for (int ir = D0; ir < D0 + ND + NR - 1; ++ir) {
        const f16x8 Ah = *(const f16x8*)(&s_hi[wrow + ir][0] + aoff);
        const f16x8 Al = *(const f16x8*)(&s_lo[wrow + ir][0] + aoff);
#pragma unroll
        for (int r = 0; r < NR; ++r) {
            const int dy = ir - r;
            if (dy >= D0 && dy < D0 + ND) {
                acc[r] = mfma16(Ah, Bh[dy - D0], acc[r]);
                acc[r] = mfma16(Ah, Bl[dy - D0], acc[r]);
                acc[r] = mfma16(Al, Bh[dy - D0], acc[r]);
            }
        }
    }
    if (PRIO) __builtin_amdgcn_s_setprio(0);
}

// --- prep: per-batch filters, composite weights, pre-split B-fragments
//     fragW1: [9][st 2][hl 2][lane 64] f16x8      (batch-independent)
//     fragW2: [16][11][st 2][hl 2][lane 64] f16x8 (per-batch composite)
__global__ __launch_bounds__(256) void k_prep(
    const float* __restrict__ params, const float* __restrict__ W_emb,
    const float* __restrict__ b_emb, const float* __restrict__ KT,
    const float* __restrict__ bT, const float* __restrict__ W1,
    const float* __restrict__ W2,
    f16x8* __restrict__ fragW1, f16x8* __restrict__ fragW2)
{
    __shared__ float s_emb[128];
    __shared__ float s_filt[36];      // [i2*3+j2][c]
    __shared__ float s_wc[1936];      // [dy][dx][c][f], 11x11x4x4
    const int t = threadIdx.x, b = blockIdx.x;

    if (t < 128) {
        float sv = b_emb[t];
#pragma unroll
        for (int p = 0; p < 8; ++p)
            sv = fmaf(params[b * 8 + p], W_emb[p * 128 + t], sv);
        s_emb[t] = silu_f(sv);
    }
    __syncthreads();
    if (t < 36) {
        const int ij = t >> 2, ff = t & 3;
        float sv = bT[ff];
        for (int c = 0; c < 128; ++c)
            sv = fmaf(s_emb[c], KT[(ij * 128 + c) * 4 + ff], sv);
        s_filt[t] = silu_f(sv);
    }
    __syncthreads();

    // composite Wc[dy][dx][c][f] = sum_{i2,j2} F[i2][j2][c] * W2[dy-i2][dx-j2][c][f]
    for (int i = t; i < 1936; i += 256) {
        const int f = i & 3, c = (i >> 2) & 3;
        const int dxy = i >> 4, dx = dxy % 11, dy = dxy / 11;
        float sv = 0.f;
#pragma unroll
        for (int i2 = 0; i2 < 3; ++i2)
#pragma unroll
            for (int j2 = 0; j2 < 3; ++j2) {
                const int a = dy - i2, bb = dx - j2;
                if (a >= 0 && a < 9 && bb >= 0 && bb < 9)
                    sv = fmaf(s_filt[(i2 * 3 + j2) * 4 + c],
                              W2[((a * 9 + bb) * 4 + c) * 4 + f], sv);
            }
        s_wc[i] = sv;
    }
    __syncthreads();

    // B-fragments for the composite (per batch)
    for (int fi = t; fi < 11 * 256; fi += 256) {
        const int dy = fi >> 8, rem = fi & 255;
        const int st = (rem >> 7) & 1, hl = (rem >> 6) & 1, lane = rem & 63;
        const int g = lane >> 4, n = lane & 15, s = n >> 2, f = n & 3;
        f16x8 v;
#pragma unroll
        for (int j = 0; j < 8; ++j) {
            const int k = st * 32 + g * 8 + j;
            const int e = k >> 2, c = k & 3, dx = e - s;
            const float wv = (dx >= 0 && dx < 11)
                ? s_wc[((dy * 11 + dx) * 4 + c) * 4 + f] : 0.f;
            const f16x2 hlv = split_f(wv);
            v[j] = hl ? hlv[1] : hlv[0];
        }
        fragW2[((size_t)b * 11 + dy) * 256 + rem] = v;
    }

    // B-fragments for W1 (batch-independent; block 0 only)
    if (b == 0) {
        for (int fi = t; fi < 9 * 256; fi += 256) {
            const int dy = fi >> 8, rem = fi & 255;
            const int st = (rem >> 7) & 1, hl = (rem >> 6) & 1, lane = rem & 63;
            const int g = lane >> 4, n = lane & 15, s = n >> 2, f = n & 3;
            f16x8 v;
#pragma unroll
            for (int j = 0; j < 8; ++j) {
                const int k = st * 32 + g * 8 + j;
                const int e = k >> 2, c = k & 3, dx = e - s;
                const float wv = (dx >= 0 && dx < 9)
                    ? W1[((dy * 9 + dx) * 4 + c) * 4 + f] : 0.f;
                const f16x2 hlv = split_f(wv);
                v[j] = hl ? hlv[1] : hlv[0];
            }
            fragW1[(size_t)dy * 256 + rem] = v;
        }
    }
}

// --- conv1: [16,512,512,4] f32 -> relu -> y1 [16,504,504] x (h,l)x4 f16
//     32-row tiles, NO setprio (R13 exact config, best measured: ~49us)
__global__ __launch_bounds__(256, 2) void k_conv1(
    const float* __restrict__ in, const float* __restrict__ b1,
    const f16x8* __restrict__ fragW1, f16* __restrict__ y1)
{
    __shared__ f16x4 s_hi[40][76];
    __shared__ f16x4 s_lo[40][76];
    const int t = threadIdx.x;
    const int x0 = blockIdx.x * 64, y0 = blockIdx.y * 32, b = blockIdx.z;

    const float4* inp = (const float4*)in + (size_t)b * (512 * 512);
    for (int i = t; i < 40 * 76; i += 256) {
        const int rr = i / 76, cc = i % 76;
        const int gy = y0 + rr, gx = x0 + cc;
        float4 v = make_float4(0.f, 0.f, 0.f, 0.f);
        if (gy < 512 && gx < 512) v = inp[gy * 512 + gx];
        f16x4 h, l;
        const f16x2 p0 = split_f(v.x), p1 = split_f(v.y);
        const f16x2 p2 = split_f(v.z), p3 = split_f(v.w);
        h[0] = p0[0]; l[0] = p0[1]; h[1] = p1[0]; l[1] = p1[1];
        h[2] = p2[0]; l[2] = p2[1]; h[3] = p3[0]; l[3] = p3[1];
        s_hi[rr][cc] = h; s_lo[rr][cc] = l;
    }

    const int lane = t & 63, w = t >> 6;
    const int g = lane >> 4, n = lane & 15, s = n >> 2, f = n & 3;

    __syncthreads();

    const float bias = b1[f];
    f32x4 acc[8];
#pragma unroll
    for (int r = 0; r < 8; ++r) acc[r] = (f32x4){bias, bias, bias, bias};

    const int ai = 4 * (lane & 15) + 2 * g;
#pragma unroll
    for (int st = 0; st < 2; ++st) {
        const f16x8* bbase = fragW1 + st * 128 + lane;
        const int aoff = ai + st * 8;
        conv_chunk<0, 5, 8, false>(bbase, s_hi, s_lo, w * 8, aoff, acc);
        conv_chunk<5, 4, 8, false>(bbase, s_hi, s_lo, w * 8, aoff, acc);
    }

    // D: col n=(s,f); row m=4g+q; x = x0+16g+4q+s; store (h,l) f16x2
    const int xb = x0 + 16 * g + s;
#pragma unroll
    for (int r = 0; r < 8; ++r) {
        const int yr = y0 + w * 8 + r;
        if (yr >= 504) continue;
        const size_t rowbase = ((size_t)(b * 504 + yr) * 504) * 8 + f * 2;
#pragma unroll
        for (int q = 0; q < 4; ++q) {
            const int x = xb + 4 * q;
            if (x < 504) {
                const float v = fmaxf(acc[r][q], 0.f);
                *(f16x2*)(y1 + rowbase + (size_t)x * 8) = split_f(v);
            }
        }
    }
}

// --- composite 11x11 per-batch conv on y1 + relu + pixnorm -> out f32
//     16-row tiles + setprio (R14 exact config, best measured: 71.5us)
__global__ __launch_bounds__(256, 2) void k_dwconv2(
    const f16* __restrict__ y1, const float* __restrict__ b2,
    const f16x8* __restrict__ fragW2, float* __restrict__ out)
{
    __shared__ f16x4 s_hi[26][76];
    __shared__ f16x4 s_lo[26][76];
    const int t = threadIdx.x;
    const int x0 = blockIdx.x * 64, y0 = blockIdx.y * 16, b = blockIdx.z;

    // stage y1 with halo (-1 .. +9 beyond tile), zero outside [0,504)^2
    for (int i = t; i < 26 * 76; i += 256) {
        const int rr = i / 76, cc = i % 76;
        const int gy = y0 - 1 + rr, gx = x0 - 1 + cc;
        f16x4 h, l;
        if (gy >= 0 && gy < 504 && gx >= 0 && gx < 504) {
            const f16x8 p = *(const f16x8*)(y1 + ((size_t)(b * 504 + gy) * 504 +
                                                  (size_t)gx) * 8);
            h[0] = p[0]; l[0] = p[1]; h[1] = p[2]; l[1] = p[3];
            h[2] = p[4]; l[2] = p[5]; h[3] = p[6]; l[3] = p[7];
        } else {
            h[0] = h[1] = h[2] = h[3] = (f16)0.f;
            l[0] = l[1] = l[2] = l[3] = (f16)0.f;
        }
        s_hi[rr][cc] = h; s_lo[rr][cc] = l;
    }

    const int lane = t & 63, w = t >> 6;
    const int g = lane >> 4, n = lane & 15, s = n >> 2, f = n & 3;
    const f16x8* fr = fragW2 + (size_t)b * 11 * 256;

    __syncthreads();

    const float bias = b2[f];
    f32x4 acc[4];
#pragma unroll
    for (int r = 0; r < 4; ++r) acc[r] = (f32x4){bias, bias, bias, bias};

    const int ai = 4 * (lane & 15) + 2 * g;
#pragma unroll
    for (int st = 0; st < 2; ++st) {
        const f16x8* bbase = fr + st * 128 + lane;
        const int aoff = ai + st * 8;
        conv_chunk<0, 4, 4, true>(bbase, s_hi, s_lo, w * 4, aoff, acc);
        conv_chunk<4, 4, 4, true>(bbase, s_hi, s_lo, w * 4, aoff, acc);
        conv_chunk<8, 3, 4, true>(bbase, s_hi, s_lo, w * 4, aoff, acc);
    }

    // epilogue: relu -> pixnorm across channels (lanes n^1, n^2) -> f32 store
    const int xb = x0 + 16 * g + s;
#pragma unroll
    for (int r = 0; r < 4; ++r) {
        const int yr = y0 + w * 4 + r;
        const size_t rowbase = ((size_t)((size_t)b * 496 + yr) * 496) * 4 + f;
#pragma unroll
        for (int q = 0; q < 4; ++q) {
            float v = fmaxf(acc[r][q], 0.f);
            float sq = v * v;
            sq += __shfl_xor(sq, 1);
            sq += __shfl_xor(sq, 2);
            const float sc = rsqrtf(sq * 0.25f + 1e-8f);
            const int x = xb + 4 * q;
            if (yr < 496 && x < 496) out[rowbase + (size_t)x * 4] = v * sc;
        }
    }
}

extern "C" void kernel_launch(void* const* d_in, const int* in_sizes, int n_in,
                              void* d_out, int out_size, void* d_ws, size_t ws_size,
                              hipStream_t stream)
{
    const float* noise  = (const float*)d_in[0];
    const float* params = (const float*)d_in[1];
    const float* W_emb  = (const float*)d_in[2];
    const float* b_emb  = (const float*)d_in[3];
    const float* KT     = (const float*)d_in[4];
    const float* bT     = (const float*)d_in[5];
    const float* W1     = (const float*)d_in[6];
    const float* b1     = (const float*)d_in[7];
    const float* W2     = (const float*)d_in[8];
    const float* b2     = (const float*)d_in[9];

    float* out = (float*)d_out;
    f16*   y1  = (f16*)d_ws;  // 16*504*504*8 f16 = 65,028,096 B
    f16x8* fragW2 = (f16x8*)((char*)d_ws + 65028096);           // 720,896 B
    f16x8* fragW1 = (f16x8*)((char*)d_ws + 65028096 + 720896);  //  36,864 B

    k_prep<<<dim3(16), dim3(256), 0, stream>>>(params, W_emb, b_emb, KT, bT,
                                               W1, W2, fragW1, fragW2);

    dim3 grid(8, 16, 16);   // ceil(504/64), ceil(504/32), B
    k_conv1<<<grid, dim3(256), 0, stream>>>(noise, b1, fragW1, y1);

    dim3 grid2(8, 31, 16);  // ceil(496/64), 496/16, B
    k_dwconv2<<<grid2, dim3(256), 0, stream>>>(y1, b2, fragW2, out);
}